// Round 6
// baseline (9805.895 us; speedup 1.0000x reference)
//
#include <hip/hip_runtime.h>
#include <hip/hip_bf16.h>

typedef __bf16 bf16x8 __attribute__((ext_vector_type(8)));
typedef float f32x4 __attribute__((ext_vector_type(4)));

#define MFMA16(a, b, c) __builtin_amdgcn_mfma_f32_16x16x32_bf16((a), (b), (c), 0, 0, 0)

#define HN_OFF 8388608ull   // 32*512*512
#define CN_OFF 8421376ull   // HN_OFF + 2*32*512
#define TSTR   136          // LDS tile row stride (128 + 8 pad), elements

__device__ __forceinline__ float sigf(float x) { return 1.0f / (1.0f + __expf(-x)); }

__device__ __forceinline__ float b2f(unsigned short u) {
    union { unsigned u; float f; } c; c.u = ((unsigned)u) << 16; return c.f;
}

// split fp32 -> (hi, lo) bf16 pair; hi+lo reconstructs to ~2^-16 relative
__device__ __forceinline__ void split8(const float* p, bf16x8& hi, bf16x8& lo) {
    union { __hip_bfloat16 h[8]; bf16x8 v; } uh, ul;
    #pragma unroll
    for (int i = 0; i < 8; ++i) {
        __hip_bfloat16 e = __float2bfloat16(p[i]);
        uh.h[i] = e;
        ul.h[i] = __float2bfloat16(p[i] - __bfloat162float(e));
    }
    hi = uh.v; lo = ul.v;
}

// ---- software grid barrier: 64 resident blocks, release/acquire + fences ----
__device__ __forceinline__ void gridbar(unsigned* flags, unsigned phase) {
    __syncthreads();                        // all block stores drained before publish
    if (threadIdx.x == 0) {
        __threadfence();                    // release: write back dirty lines
        __hip_atomic_store(&flags[blockIdx.x * 16], phase,
                           __ATOMIC_RELEASE, __HIP_MEMORY_SCOPE_AGENT);
    }
    if (threadIdx.x < 64) {                 // wave 0: lane i polls block i
        while (__hip_atomic_load(&flags[threadIdx.x * 16],
                                 __ATOMIC_ACQUIRE, __HIP_MEMORY_SCOPE_AGENT) < phase)
            __builtin_amdgcn_s_sleep(1);
    }
    __syncthreads();                        // everyone waits for the poll
    __threadfence();                        // acquire: invalidate stale cached lines
}

// ---------------- dtype probe: 1 = fp32 inputs, 0 = bf16 inputs; zero flags ----------------
__global__ __launch_bounds__(256) void lstm_detect(
    const unsigned* __restrict__ Wq, unsigned* __restrict__ dflag,
    unsigned* __restrict__ flags)
{
    for (int j = threadIdx.x; j < 1024; j += 256) flags[j] = 0;
    if (threadIdx.x == 0) {
        int cnt = 0;
        for (int i = 0; i < 256; ++i) {
            unsigned u = Wq[(size_t)i * 4093];      // < 2^20 words: in-bounds either way
            float v = b2f((unsigned short)(u & 0xFFFFu));
            if (!(v == v) || fabsf(v) > 100.0f) ++cnt;   // fp32 mantissa: ~47% hit
        }
        *dflag = (cnt > 32) ? 1u : 0u;
    }
}

// ---------------- init: inputs -> hi/lo state, fp32 c ----------------
__global__ __launch_bounds__(256) void lstm_init(
    const void* __restrict__ h0v, const void* __restrict__ c0v,
    __hip_bfloat16* __restrict__ h0hi, __hip_bfloat16* __restrict__ h0lo,
    __hip_bfloat16* __restrict__ h1hi, __hip_bfloat16* __restrict__ h1lo,
    float* __restrict__ cws, const unsigned* __restrict__ dflag)
{
    const bool f32 = (*dflag != 0);
    int i = blockIdx.x * 256 + threadIdx.x;   // i = b*512 + n
    int b = i >> 9, n = i & 511;
    float f0, f1, g0, g1;
    if (f32) {
        const float* h = (const float*)h0v; const float* c = (const float*)c0v;
        f0 = h[(b * 2 + 0) * 512 + n];  f1 = h[(b * 2 + 1) * 512 + n];
        g0 = c[(b * 2 + 0) * 512 + n];  g1 = c[(b * 2 + 1) * 512 + n];
    } else {
        const unsigned short* h = (const unsigned short*)h0v;
        const unsigned short* c = (const unsigned short*)c0v;
        f0 = b2f(h[(b * 2 + 0) * 512 + n]);  f1 = b2f(h[(b * 2 + 1) * 512 + n]);
        g0 = b2f(c[(b * 2 + 0) * 512 + n]);  g1 = b2f(c[(b * 2 + 1) * 512 + n]);
    }
    __hip_bfloat16 e0 = __float2bfloat16(f0), e1 = __float2bfloat16(f1);
    h0hi[i] = e0; h0lo[i] = __float2bfloat16(f0 - __bfloat162float(e0));
    h1hi[i] = e1; h1lo[i] = __float2bfloat16(f1 - __bfloat162float(e1));
    cws[i] = g0;  cws[16384 + i] = g1;
}

// ---------------- persistent scan: 64 WGs (even=layer0, odd=layer1) ----------------
__global__ __launch_bounds__(256, 1) void lstm_seq(
    const void* __restrict__ xv,
    const void* __restrict__ Wxv, const void* __restrict__ bxv,
    const void* __restrict__ Whv, const void* __restrict__ bhv,
    __hip_bfloat16* __restrict__ h0hi, __hip_bfloat16* __restrict__ h0lo,
    __hip_bfloat16* __restrict__ h1hi, __hip_bfloat16* __restrict__ h1lo,
    const float* __restrict__ cws, unsigned* __restrict__ flags,
    const unsigned* __restrict__ dflag, void* __restrict__ outv)
{
    const bool f32 = (*dflag != 0);
    const int p  = blockIdx.x & 1;
    const int wt = blockIdx.x >> 1;
    const int tid = threadIdx.x;
    const int q = tid >> 6, lane = tid & 63;
    const int n16 = lane & 15, quad = lane >> 4;
    const int colg = q * 512 + wt * 16 + n16;     // gate column within this layer

    float* outf = (float*)outv;
    __hip_bfloat16* outh = (__hip_bfloat16*)outv;

    __shared__ __align__(16) char smem[43008];
    __hip_bfloat16* tAh = (__hip_bfloat16*)(smem);
    __hip_bfloat16* tAl = (__hip_bfloat16*)(smem + 8704);
    __hip_bfloat16* tRh = (__hip_bfloat16*)(smem + 17408);
    __hip_bfloat16* tRl = (__hip_bfloat16*)(smem + 26112);
    float* gbuf = (float*)(smem + 34816);         // [4][32][16] f32

    // --- weights -> hi/lo bf16 fragments, held for all 512 steps ---
    bf16x8 wah[16], wal[16], wrh[16], wrl[16];
    if (f32) {
        const float* WA = (const float*)Wxv + ((size_t)(p * 2048 + colg)) * 512;
        const float* WR = (const float*)Whv + ((size_t)(p * 2048 + colg)) * 512;
        #pragma unroll
        for (int kk = 0; kk < 16; ++kk) {
            split8(WA + kk * 32 + quad * 8, wah[kk], wal[kk]);
            split8(WR + kk * 32 + quad * 8, wrh[kk], wrl[kk]);
        }
    } else {
        const unsigned short* WA = (const unsigned short*)Wxv + ((size_t)(p * 2048 + colg)) * 512;
        const unsigned short* WR = (const unsigned short*)Whv + ((size_t)(p * 2048 + colg)) * 512;
        union { uint4 u; bf16x8 v; } cv;
        bf16x8 z = {};
        #pragma unroll
        for (int kk = 0; kk < 16; ++kk) {
            cv.u = *(const uint4*)(WA + kk * 32 + quad * 8); wah[kk] = cv.v; wal[kk] = z;
            cv.u = *(const uint4*)(WR + kk * 32 + quad * 8); wrh[kk] = cv.v; wrl[kk] = z;
        }
    }
    float bias;
    if (f32) bias = ((const float*)bxv)[p * 2048 + colg] + ((const float*)bhv)[p * 2048 + colg];
    else     bias = b2f(((const unsigned short*)bxv)[p * 2048 + colg])
                  + b2f(((const unsigned short*)bhv)[p * 2048 + colg]);

    int pb[2], pn2[2];
    {
        int e0 = tid * 2;
        pb[0] = e0 >> 4;      pb[1] = (e0 + 1) >> 4;
        pn2[0] = e0 & 15;     pn2[1] = (e0 + 1) & 15;
    }
    float cv2[2];
    #pragma unroll
    for (int j = 0; j < 2; ++j)
        cv2[j] = cws[p * 16384 + pb[j] * 512 + wt * 16 + pn2[j]];

    for (int k = 0; k <= 512; ++k) {
        const bool doComp = (p == 0) ? (k < 512) : (k > 0);

        if (doComp) {
            const __hip_bfloat16* Ahi = h0hi + (k & 1) * 16384;          // p==1 input
            const __hip_bfloat16* Alo = h0lo + (k & 1) * 16384;
            const __hip_bfloat16* Rhi = (p == 0) ? h0hi + (k & 1) * 16384
                                                 : h1hi + ((k + 1) & 1) * 16384;
            const __hip_bfloat16* Rlo = (p == 0) ? h0lo + (k & 1) * 16384
                                                 : h1lo + ((k + 1) & 1) * 16384;

            f32x4 acc0 = {bias, bias, bias, bias};
            f32x4 acc1 = {bias, bias, bias, bias};

            for (int kq = 0; kq < 4; ++kq) {           // K staged in quarters of 128
                __syncthreads();
                #pragma unroll
                for (int j = 0; j < 2; ++j) {
                    int flat = tid + j * 256;           // 512 vec8: 32 rows x 16
                    int b = flat >> 4, d8 = (flat & 15) * 8;
                    int kg = kq * 128 + d8;
                    if (p == 0) {                       // A = x_t
                        if (f32) {
                            const float* xp = (const float*)xv
                                + (size_t)b * 262144 + (size_t)k * 512 + kg;
                            union { __hip_bfloat16 h[8]; uint4 u; } ph, pl;
                            #pragma unroll
                            for (int i = 0; i < 8; ++i) {
                                float v = xp[i];
                                __hip_bfloat16 e = __float2bfloat16(v);
                                ph.h[i] = e;
                                pl.h[i] = __float2bfloat16(v - __bfloat162float(e));
                            }
                            *(uint4*)&tAh[b * TSTR + d8] = ph.u;
                            *(uint4*)&tAl[b * TSTR + d8] = pl.u;
                        } else {
                            const unsigned short* xp = (const unsigned short*)xv
                                + (size_t)b * 262144 + (size_t)k * 512 + kg;
                            uint4 z = {0u, 0u, 0u, 0u};
                            *(uint4*)&tAh[b * TSTR + d8] = *(const uint4*)xp;
                            *(uint4*)&tAl[b * TSTR + d8] = z;
                        }
                    } else {                            // A = h0(k-1), hi/lo copy
                        *(uint4*)&tAh[b * TSTR + d8] = *(const uint4*)(Ahi + b * 512 + kg);
                        *(uint4*)&tAl[b * TSTR + d8] = *(const uint4*)(Alo + b * 512 + kg);
                    }
                    *(uint4*)&tRh[b * TSTR + d8] = *(const uint4*)(Rhi + b * 512 + kg);
                    *(uint4*)&tRl[b * TSTR + d8] = *(const uint4*)(Rlo + b * 512 + kg);
                }
                __syncthreads();
                #pragma unroll
                for (int kk2 = 0; kk2 < 4; ++kk2) {
                    const int kw = kq * 4 + kk2;
                    const int o = kk2 * 32 + quad * 8;
                    bf16x8 Aha = *(const bf16x8*)&tAh[n16 * TSTR + o];
                    bf16x8 Ahb = *(const bf16x8*)&tAh[(16 + n16) * TSTR + o];
                    bf16x8 Ala = *(const bf16x8*)&tAl[n16 * TSTR + o];
                    bf16x8 Alb = *(const bf16x8*)&tAl[(16 + n16) * TSTR + o];
                    bf16x8 Rha = *(const bf16x8*)&tRh[n16 * TSTR + o];
                    bf16x8 Rhb = *(const bf16x8*)&tRh[(16 + n16) * TSTR + o];
                    bf16x8 Rla = *(const bf16x8*)&tRl[n16 * TSTR + o];
                    bf16x8 Rlb = *(const bf16x8*)&tRl[(16 + n16) * TSTR + o];
                    acc0 = MFMA16(Aha, wah[kw], acc0);
                    acc0 = MFMA16(Aha, wal[kw], acc0);
                    acc0 = MFMA16(Ala, wah[kw], acc0);
                    acc0 = MFMA16(Rha, wrh[kw], acc0);
                    acc0 = MFMA16(Rha, wrl[kw], acc0);
                    acc0 = MFMA16(Rla, wrh[kw], acc0);
                    acc1 = MFMA16(Ahb, wah[kw], acc1);
                    acc1 = MFMA16(Ahb, wal[kw], acc1);
                    acc1 = MFMA16(Alb, wah[kw], acc1);
                    acc1 = MFMA16(Rhb, wrh[kw], acc1);
                    acc1 = MFMA16(Rhb, wrl[kw], acc1);
                    acc1 = MFMA16(Rlb, wrh[kw], acc1);
                }
            }

            #pragma unroll
            for (int r = 0; r < 4; ++r) {
                gbuf[(q * 32 + quad * 4 + r) * 16 + n16]      = acc0[r];
                gbuf[(q * 32 + 16 + quad * 4 + r) * 16 + n16] = acc1[r];
            }
            __syncthreads();

            __hip_bfloat16* Ohi = (p == 0) ? h0hi + ((k + 1) & 1) * 16384
                                           : h1hi + (k & 1) * 16384;
            __hip_bfloat16* Olo = (p == 0) ? h0lo + ((k + 1) & 1) * 16384
                                           : h1lo + (k & 1) * 16384;
            #pragma unroll
            for (int j = 0; j < 2; ++j) {
                int b = pb[j], n = pn2[j];
                float ig = gbuf[(0 * 32 + b) * 16 + n];
                float fg = gbuf[(1 * 32 + b) * 16 + n];
                float gg = gbuf[(2 * 32 + b) * 16 + n];
                float og = gbuf[(3 * 32 + b) * 16 + n];
                float cnew = sigf(fg) * cv2[j] + sigf(ig) * tanhf(gg);
                cv2[j] = cnew;
                float hnew = sigf(og) * tanhf(cnew);
                __hip_bfloat16 hb = __float2bfloat16(hnew);
                __hip_bfloat16 lb = __float2bfloat16(hnew - __bfloat162float(hb));
                int idx = b * 512 + wt * 16 + n;
                Ohi[idx] = hb;
                Olo[idx] = lb;
                if (p == 1) {
                    size_t oidx = ((size_t)b * 512 + (k - 1)) * 512 + wt * 16 + n;
                    if (f32) outf[oidx] = hnew; else outh[oidx] = hb;
                    if (k == 512) {
                        if (f32) {
                            outf[HN_OFF + 16384 + idx] = hnew;
                            outf[CN_OFF + 16384 + idx] = cnew;
                        } else {
                            outh[HN_OFF + 16384 + idx] = hb;
                            outh[CN_OFF + 16384 + idx] = __float2bfloat16(cnew);
                        }
                    }
                } else if (k == 511) {
                    if (f32) {
                        outf[HN_OFF + idx] = hnew;
                        outf[CN_OFF + idx] = cnew;
                    } else {
                        outh[HN_OFF + idx] = hb;
                        outh[CN_OFF + idx] = __float2bfloat16(cnew);
                    }
                }
            }
        }

        if (k < 512) gridbar(flags, (unsigned)(k + 1));
    }
}

extern "C" void kernel_launch(void* const* d_in, const int* in_sizes, int n_in,
                              void* d_out, int out_size, void* d_ws, size_t ws_size,
                              hipStream_t stream)
{
    const void* x  = d_in[0];
    const void* h0 = d_in[1];
    const void* c0 = d_in[2];
    const void* Wx = d_in[3];
    const void* bx = d_in[4];
    const void* Wh = d_in[5];
    const void* bh = d_in[6];

    char* ws = (char*)d_ws;                                    // total need: ~398 KB
    __hip_bfloat16* h0hi = (__hip_bfloat16*)(ws);              // [2][16384] bf16
    __hip_bfloat16* h0lo = (__hip_bfloat16*)(ws + 65536);
    __hip_bfloat16* h1hi = (__hip_bfloat16*)(ws + 131072);
    __hip_bfloat16* h1lo = (__hip_bfloat16*)(ws + 196608);
    float*          cws  = (float*)(ws + 262144);              // [2][16384] f32
    unsigned*       flags = (unsigned*)(ws + 393216);          // 64 slots x 16 words
    unsigned*       dflag = (unsigned*)(ws + 397312);

    lstm_detect<<<1, 256, 0, stream>>>((const unsigned*)Wx, dflag, flags);
    lstm_init<<<64, 256, 0, stream>>>(h0, c0, h0hi, h0lo, h1hi, h1lo, cws, dflag);
    lstm_seq<<<64, 256, 0, stream>>>(x, Wx, bx, Wh, bh,
                                     h0hi, h0lo, h1hi, h1lo, cws, flags, dflag, d_out);
}

// Round 7
// 9092.689 us; speedup vs baseline: 1.0784x; 1.0784x over previous
//
#include <hip/hip_runtime.h>
#include <hip/hip_bf16.h>

typedef __bf16 bf16x8 __attribute__((ext_vector_type(8)));
typedef float f32x4 __attribute__((ext_vector_type(4)));

#define MFMA16(a, b, c) __builtin_amdgcn_mfma_f32_16x16x32_bf16((a), (b), (c), 0, 0, 0)

#define HN_OFF 8388608ull   // 32*512*512
#define CN_OFF 8421376ull   // HN_OFF + 2*32*512

__device__ __forceinline__ float sigf(float x) { return 1.0f / (1.0f + __expf(-x)); }
__device__ __forceinline__ float b2f(unsigned short u) {
    union { unsigned u; float f; } c; c.u = ((unsigned)u) << 16; return c.f;
}
__device__ __forceinline__ unsigned short f2u(float f) {
    __hip_bfloat16 h = __float2bfloat16(f); return *(unsigned short*)&h;
}

// split fp32 -> (hi, lo) bf16 pair
__device__ __forceinline__ void split8(const float* p, bf16x8& hi, bf16x8& lo) {
    union { __hip_bfloat16 h[8]; bf16x8 v; } uh, ul;
    #pragma unroll
    for (int i = 0; i < 8; ++i) {
        __hip_bfloat16 e = __float2bfloat16(p[i]);
        uh.h[i] = e;
        ul.h[i] = __float2bfloat16(p[i] - __bfloat162float(e));
    }
    hi = uh.v; lo = ul.v;
}

// ---- grid barrier: 64 resident blocks; release by t0, acquire by wave 0 only ----
__device__ __forceinline__ void gridbar(unsigned* flags, unsigned phase) {
    __syncthreads();                        // all block stores drained before publish
    if (threadIdx.x == 0) {
        __threadfence();                    // release: write back dirty L2 lines
        __hip_atomic_store(&flags[blockIdx.x * 16], phase,
                           __ATOMIC_RELAXED, __HIP_MEMORY_SCOPE_AGENT);
    }
    if (threadIdx.x < 64) {                 // wave 0: lane i polls block i
        while (__hip_atomic_load(&flags[threadIdx.x * 16],
                                 __ATOMIC_RELAXED, __HIP_MEMORY_SCOPE_AGENT) < phase)
            __builtin_amdgcn_s_sleep(1);
        __threadfence();                    // acquire: inv L1 (CU) + L2 (XCD) once
    }
    __syncthreads();                        // other waves released after the inv
}

// ---------------- dtype probe: 1 = fp32 inputs, 0 = bf16 inputs; zero flags ----------------
__global__ __launch_bounds__(256) void lstm_detect(
    const unsigned* __restrict__ Wq, unsigned* __restrict__ dflag,
    unsigned* __restrict__ flags)
{
    for (int j = threadIdx.x; j < 1024; j += 256) flags[j] = 0;
    if (threadIdx.x == 0) {
        int cnt = 0;
        for (int i = 0; i < 256; ++i) {
            unsigned u = Wq[(size_t)i * 4093];
            float v = b2f((unsigned short)(u & 0xFFFFu));
            if (!(v == v) || fabsf(v) > 100.0f) ++cnt;
        }
        *dflag = (cnt > 32) ? 1u : 0u;
    }
}

// ---------------- init: inputs -> hi/lo state, fp32 c ----------------
__global__ __launch_bounds__(256) void lstm_init(
    const void* __restrict__ h0v, const void* __restrict__ c0v,
    __hip_bfloat16* __restrict__ h0hi, __hip_bfloat16* __restrict__ h0lo,
    __hip_bfloat16* __restrict__ h1hi, __hip_bfloat16* __restrict__ h1lo,
    float* __restrict__ cws, const unsigned* __restrict__ dflag)
{
    const bool f32 = (*dflag != 0);
    int i = blockIdx.x * 256 + threadIdx.x;   // i = b*512 + n
    int b = i >> 9, n = i & 511;
    float f0, f1, g0, g1;
    if (f32) {
        const float* h = (const float*)h0v; const float* c = (const float*)c0v;
        f0 = h[(b * 2 + 0) * 512 + n];  f1 = h[(b * 2 + 1) * 512 + n];
        g0 = c[(b * 2 + 0) * 512 + n];  g1 = c[(b * 2 + 1) * 512 + n];
    } else {
        const unsigned short* h = (const unsigned short*)h0v;
        const unsigned short* c = (const unsigned short*)c0v;
        f0 = b2f(h[(b * 2 + 0) * 512 + n]);  f1 = b2f(h[(b * 2 + 1) * 512 + n]);
        g0 = b2f(c[(b * 2 + 0) * 512 + n]);  g1 = b2f(c[(b * 2 + 1) * 512 + n]);
    }
    __hip_bfloat16 e0 = __float2bfloat16(f0), e1 = __float2bfloat16(f1);
    h0hi[i] = e0; h0lo[i] = __float2bfloat16(f0 - __bfloat162float(e0));
    h1hi[i] = e1; h1lo[i] = __float2bfloat16(f1 - __bfloat162float(e1));
    cws[i] = g0;  cws[16384 + i] = g1;
}

// ---------------- persistent scan: 64 WGs (even=layer0, odd=layer1) ----------------
// Fragment-contiguous LDS: chunk(kk,half,l64) = kk*128 + half*64 + l64, 16B each.
// Tiles: Ah @0, Al @32K, Rh @64K, Rl @96K. gbuf separate, stride 17.
__global__ __launch_bounds__(256, 1) void lstm_seq(
    const void* __restrict__ xv,
    const void* __restrict__ Wxv, const void* __restrict__ bxv,
    const void* __restrict__ Whv, const void* __restrict__ bhv,
    __hip_bfloat16* __restrict__ h0hi, __hip_bfloat16* __restrict__ h0lo,
    __hip_bfloat16* __restrict__ h1hi, __hip_bfloat16* __restrict__ h1lo,
    const float* __restrict__ cws, unsigned* __restrict__ flags,
    const unsigned* __restrict__ dflag, void* __restrict__ outv)
{
    const bool f32 = (*dflag != 0);
    const int p  = blockIdx.x & 1;
    const int wt = blockIdx.x >> 1;
    const int tid = threadIdx.x;
    const int q = tid >> 6, lane = tid & 63;
    const int n16 = lane & 15, quad = lane >> 4;
    const int colg = q * 512 + wt * 16 + n16;

    __shared__ __align__(16) char smem[131072];
    __shared__ float gbuf[2176];              // [4 gates][32 rows] stride 17

    float* outf = (float*)outv;
    __hip_bfloat16* outh = (__hip_bfloat16*)outv;

    // --- weights -> hi(/lo) bf16 fragments, register-resident for all 512 steps ---
    bf16x8 wa[16], wal[16], wr[16], wrl[16];
    if (f32) {
        const float* WA = (const float*)Wxv + ((size_t)(p * 2048 + colg)) * 512;
        const float* WR = (const float*)Whv + ((size_t)(p * 2048 + colg)) * 512;
        #pragma unroll
        for (int kk = 0; kk < 16; ++kk) {
            split8(WA + kk * 32 + quad * 8, wa[kk], wal[kk]);
            split8(WR + kk * 32 + quad * 8, wr[kk], wrl[kk]);
        }
    } else {
        const unsigned short* WA = (const unsigned short*)Wxv + ((size_t)(p * 2048 + colg)) * 512;
        const unsigned short* WR = (const unsigned short*)Whv + ((size_t)(p * 2048 + colg)) * 512;
        union { uint4 u; bf16x8 v; } cvu;
        #pragma unroll
        for (int kk = 0; kk < 16; ++kk) {
            cvu.u = *(const uint4*)(WA + kk * 32 + quad * 8); wa[kk] = cvu.v;
            cvu.u = *(const uint4*)(WR + kk * 32 + quad * 8); wr[kk] = cvu.v;
        }
    }
    float bias;
    if (f32) bias = ((const float*)bxv)[p * 2048 + colg] + ((const float*)bhv)[p * 2048 + colg];
    else     bias = b2f(((const unsigned short*)bxv)[p * 2048 + colg])
                  + b2f(((const unsigned short*)bhv)[p * 2048 + colg]);

    // pointwise mapping: elems (b, n0) and (b, n0+1); fp32 c-state in registers
    const int e0 = tid * 2;
    const int pbb = e0 >> 4;
    const int pn0 = e0 & 15;
    float cv[2];
    cv[0] = cws[p * 16384 + pbb * 512 + wt * 16 + pn0];
    cv[1] = cws[p * 16384 + pbb * 512 + wt * 16 + pn0 + 1];

    const unsigned short* xb = (const unsigned short*)xv;

    // x prefetch (p==0, bf16 mode): stage x(t) into Ah tile
    #define STAGE_X_BF16(T)                                                      \
        { _Pragma("unroll")                                                      \
          for (int j = 0; j < 8; ++j) {                                          \
              int L = j * 256 + tid;                                             \
              int rem = L & 127;                                                 \
              int row = ((rem >> 6) << 4) + (rem & 15);                          \
              int kcol = ((L >> 7) << 5) + (((rem >> 4) & 3) << 3);              \
              *(uint4*)(smem + (L << 4)) =                                       \
                  *(const uint4*)(xb + ((size_t)row * 512 + (T)) * 512 + kcol);  \
          } }

    if (p == 0 && !f32) STAGE_X_BF16(0);

    for (int k = 0; k <= 512; ++k) {
        const bool doComp = (p == 0) ? (k < 512) : (k > 0);

        if (doComp) {
            const int t = (p == 0) ? k : (k - 1);
            const __hip_bfloat16* Ahi = h0hi + (k & 1) * 16384;          // p==1 A
            const __hip_bfloat16* Alo = h0lo + (k & 1) * 16384;
            const __hip_bfloat16* Rhi = (p == 0) ? h0hi + (k & 1) * 16384
                                                 : h1hi + ((k + 1) & 1) * 16384;
            const __hip_bfloat16* Rlo = (p == 0) ? h0lo + (k & 1) * 16384
                                                 : h1lo + ((k + 1) & 1) * 16384;

            // ---- single-stage staging, lane-linear 16B chunks ----
            #pragma unroll
            for (int j = 0; j < 8; ++j) {
                int L = j * 256 + tid;
                int rem = L & 127;
                int row = ((rem >> 6) << 4) + (rem & 15);
                int kcol = ((L >> 7) << 5) + (((rem >> 4) & 3) << 3);
                size_t hoff = (size_t)row * 512 + kcol;
                *(uint4*)(smem + 65536 + (L << 4)) = *(const uint4*)(Rhi + hoff);
                *(uint4*)(smem + 98304 + (L << 4)) = *(const uint4*)(Rlo + hoff);
                if (p == 1) {
                    *(uint4*)(smem + (L << 4))         = *(const uint4*)(Ahi + hoff);
                    *(uint4*)(smem + 32768 + (L << 4)) = *(const uint4*)(Alo + hoff);
                } else if (f32) {
                    const float* xp = (const float*)xv + ((size_t)row * 512 + t) * 512 + kcol;
                    bf16x8 hi, lo;
                    split8(xp, hi, lo);
                    *(bf16x8*)(smem + (L << 4)) = hi;
                    *(bf16x8*)(smem + 32768 + (L << 4)) = lo;
                }
                // p==0 bf16: Ah prefetched, Al unused
            }
            __syncthreads();

            // ---- MFMA chains (fragment reads lane-linear) ----
            const char* sl = smem + (lane << 4);
            f32x4 acc0 = {bias, bias, bias, bias};
            f32x4 acc1 = {bias, bias, bias, bias};
            if (f32) {
                #pragma unroll
                for (int kk = 0; kk < 16; ++kk) {
                    bf16x8 Aha = *(const bf16x8*)(sl + kk * 2048);
                    bf16x8 Ahb = *(const bf16x8*)(sl + kk * 2048 + 1024);
                    bf16x8 Ala = *(const bf16x8*)(sl + 32768 + kk * 2048);
                    bf16x8 Alb = *(const bf16x8*)(sl + 32768 + kk * 2048 + 1024);
                    bf16x8 Rha = *(const bf16x8*)(sl + 65536 + kk * 2048);
                    bf16x8 Rhb = *(const bf16x8*)(sl + 65536 + kk * 2048 + 1024);
                    bf16x8 Rla = *(const bf16x8*)(sl + 98304 + kk * 2048);
                    bf16x8 Rlb = *(const bf16x8*)(sl + 98304 + kk * 2048 + 1024);
                    acc0 = MFMA16(Aha, wa[kk], acc0);
                    acc0 = MFMA16(Aha, wal[kk], acc0);
                    acc0 = MFMA16(Ala, wa[kk], acc0);
                    acc0 = MFMA16(Rha, wr[kk], acc0);
                    acc0 = MFMA16(Rha, wrl[kk], acc0);
                    acc0 = MFMA16(Rla, wr[kk], acc0);
                    acc1 = MFMA16(Ahb, wa[kk], acc1);
                    acc1 = MFMA16(Ahb, wal[kk], acc1);
                    acc1 = MFMA16(Alb, wa[kk], acc1);
                    acc1 = MFMA16(Rhb, wr[kk], acc1);
                    acc1 = MFMA16(Rhb, wrl[kk], acc1);
                    acc1 = MFMA16(Rlb, wr[kk], acc1);
                }
            } else if (p == 1) {
                #pragma unroll
                for (int kk = 0; kk < 16; ++kk) {
                    bf16x8 Aha = *(const bf16x8*)(sl + kk * 2048);
                    bf16x8 Ahb = *(const bf16x8*)(sl + kk * 2048 + 1024);
                    bf16x8 Ala = *(const bf16x8*)(sl + 32768 + kk * 2048);
                    bf16x8 Alb = *(const bf16x8*)(sl + 32768 + kk * 2048 + 1024);
                    bf16x8 Rha = *(const bf16x8*)(sl + 65536 + kk * 2048);
                    bf16x8 Rhb = *(const bf16x8*)(sl + 65536 + kk * 2048 + 1024);
                    bf16x8 Rla = *(const bf16x8*)(sl + 98304 + kk * 2048);
                    bf16x8 Rlb = *(const bf16x8*)(sl + 98304 + kk * 2048 + 1024);
                    acc0 = MFMA16(Aha, wa[kk], acc0);
                    acc0 = MFMA16(Ala, wa[kk], acc0);
                    acc0 = MFMA16(Rha, wr[kk], acc0);
                    acc0 = MFMA16(Rla, wr[kk], acc0);
                    acc1 = MFMA16(Ahb, wa[kk], acc1);
                    acc1 = MFMA16(Alb, wa[kk], acc1);
                    acc1 = MFMA16(Rhb, wr[kk], acc1);
                    acc1 = MFMA16(Rlb, wr[kk], acc1);
                }
            } else {
                #pragma unroll
                for (int kk = 0; kk < 16; ++kk) {
                    bf16x8 Aha = *(const bf16x8*)(sl + kk * 2048);
                    bf16x8 Ahb = *(const bf16x8*)(sl + kk * 2048 + 1024);
                    bf16x8 Rha = *(const bf16x8*)(sl + 65536 + kk * 2048);
                    bf16x8 Rhb = *(const bf16x8*)(sl + 65536 + kk * 2048 + 1024);
                    bf16x8 Rla = *(const bf16x8*)(sl + 98304 + kk * 2048);
                    bf16x8 Rlb = *(const bf16x8*)(sl + 98304 + kk * 2048 + 1024);
                    acc0 = MFMA16(Aha, wa[kk], acc0);
                    acc0 = MFMA16(Rha, wr[kk], acc0);
                    acc0 = MFMA16(Rla, wr[kk], acc0);
                    acc1 = MFMA16(Ahb, wa[kk], acc1);
                    acc1 = MFMA16(Rhb, wr[kk], acc1);
                    acc1 = MFMA16(Rlb, wr[kk], acc1);
                }
            }
            __syncthreads();                  // all fragment reads done (LDS reusable)

            // gates -> gbuf (C/D layout: col=lane&15, row=quad*4+reg), stride 17
            #pragma unroll
            for (int r = 0; r < 4; ++r) {
                gbuf[(q * 32 + quad * 4 + r) * 17 + n16]      = acc0[r];
                gbuf[(q * 32 + 16 + quad * 4 + r) * 17 + n16] = acc1[r];
            }
            __syncthreads();

            // ---- pointwise epilogue ----
            __hip_bfloat16* Ohi = (p == 0) ? h0hi + ((k + 1) & 1) * 16384
                                           : h1hi + (k & 1) * 16384;
            __hip_bfloat16* Olo = (p == 0) ? h0lo + ((k + 1) & 1) * 16384
                                           : h1lo + (k & 1) * 16384;
            float rh[2], rc[2];
            #pragma unroll
            for (int j = 0; j < 2; ++j) {
                int n = pn0 + j;
                float ig = gbuf[(0 * 32 + pbb) * 17 + n];
                float fg = gbuf[(1 * 32 + pbb) * 17 + n];
                float gg = gbuf[(2 * 32 + pbb) * 17 + n];
                float og = gbuf[(3 * 32 + pbb) * 17 + n];
                float cnew = sigf(fg) * cv[j] + sigf(ig) * tanhf(gg);
                cv[j] = cnew;
                rc[j] = cnew;
                rh[j] = sigf(og) * tanhf(cnew);
            }
            unsigned phi = 0, plo = 0, pcn = 0;
            #pragma unroll
            for (int j = 0; j < 2; ++j) {
                unsigned short hu = f2u(rh[j]);
                unsigned short lu = f2u(rh[j] - b2f(hu));
                phi |= ((unsigned)hu) << (16 * j);
                plo |= ((unsigned)lu) << (16 * j);
                pcn |= ((unsigned)f2u(rc[j])) << (16 * j);
            }
            const int idx = pbb * 512 + wt * 16 + pn0;
            *(unsigned*)(Ohi + idx) = phi;
            *(unsigned*)(Olo + idx) = plo;
            if (p == 1) {
                size_t oidx = ((size_t)pbb * 512 + t) * 512 + wt * 16 + pn0;
                if (f32) { outf[oidx] = rh[0]; outf[oidx + 1] = rh[1]; }
                else     { *(unsigned*)(outh + oidx) = phi; }
                if (k == 512) {
                    if (f32) {
                        outf[HN_OFF + 16384 + idx] = rh[0]; outf[HN_OFF + 16385 + idx] = rh[1];
                        outf[CN_OFF + 16384 + idx] = rc[0]; outf[CN_OFF + 16385 + idx] = rc[1];
                    } else {
                        *(unsigned*)(outh + HN_OFF + 16384 + idx) = phi;
                        *(unsigned*)(outh + CN_OFF + 16384 + idx) = pcn;
                    }
                }
            } else if (k == 511) {
                if (f32) {
                    outf[HN_OFF + idx] = rh[0]; outf[HN_OFF + idx + 1] = rh[1];
                    outf[CN_OFF + idx] = rc[0]; outf[CN_OFF + idx + 1] = rc[1];
                } else {
                    *(unsigned*)(outh + HN_OFF + idx) = phi;
                    *(unsigned*)(outh + CN_OFF + idx) = pcn;
                }
            }

            // prefetch next x tile while others finish / during barrier wait
            if (p == 0 && !f32 && k + 1 < 512) STAGE_X_BF16(k + 1);
        }

        if (k < 512) gridbar(flags, (unsigned)(k + 1));
    }
}

extern "C" void kernel_launch(void* const* d_in, const int* in_sizes, int n_in,
                              void* d_out, int out_size, void* d_ws, size_t ws_size,
                              hipStream_t stream)
{
    const void* x  = d_in[0];
    const void* h0 = d_in[1];
    const void* c0 = d_in[2];
    const void* Wx = d_in[3];
    const void* bx = d_in[4];
    const void* Wh = d_in[5];
    const void* bh = d_in[6];

    char* ws = (char*)d_ws;                                    // total need: ~398 KB
    __hip_bfloat16* h0hi = (__hip_bfloat16*)(ws);              // [2][16384] bf16
    __hip_bfloat16* h0lo = (__hip_bfloat16*)(ws + 65536);
    __hip_bfloat16* h1hi = (__hip_bfloat16*)(ws + 131072);
    __hip_bfloat16* h1lo = (__hip_bfloat16*)(ws + 196608);
    float*          cws  = (float*)(ws + 262144);              // [2][16384] f32
    unsigned*       flags = (unsigned*)(ws + 393216);          // 64 slots x 16 words
    unsigned*       dflag = (unsigned*)(ws + 397312);

    lstm_detect<<<1, 256, 0, stream>>>((const unsigned*)Wx, dflag, flags);
    lstm_init<<<64, 256, 0, stream>>>(h0, c0, h0hi, h0lo, h1hi, h1lo, cws, dflag);
    lstm_seq<<<64, 256, 0, stream>>>(x, Wx, bx, Wh, bh,
                                     h0hi, h0lo, h1hi, h1lo, cws, flags, dflag, d_out);
}

// Round 8
// 7139.456 us; speedup vs baseline: 1.3735x; 1.2736x over previous
//
#include <hip/hip_runtime.h>
#include <hip/hip_bf16.h>

typedef __bf16 bf16x8 __attribute__((ext_vector_type(8)));
typedef float f32x4 __attribute__((ext_vector_type(4)));
typedef unsigned long long u64;

#define MFMA16(a, b, c) __builtin_amdgcn_mfma_f32_16x16x32_bf16((a), (b), (c), 0, 0, 0)

#define HN_OFF 8388608ull   // 32*512*512
#define CN_OFF 8421376ull   // HN_OFF + 2*32*512

__device__ __forceinline__ float sigf(float x) { return 1.0f / (1.0f + __expf(-x)); }
__device__ __forceinline__ float b2f(unsigned short u) {
    union { unsigned u; float f; } c; c.u = ((unsigned)u) << 16; return c.f;
}
__device__ __forceinline__ unsigned short f2u(float f) {
    __hip_bfloat16 h = __float2bfloat16(f); return *(unsigned short*)&h;
}

// agent-scope (cross-XCD coherent, per-line) accessors — no cache-wide fences needed
__device__ __forceinline__ u64 gload8(const void* p) {
    return __hip_atomic_load((const u64*)p, __ATOMIC_RELAXED, __HIP_MEMORY_SCOPE_AGENT);
}
__device__ __forceinline__ void gstore4(void* p, unsigned v) {
    __hip_atomic_store((unsigned*)p, v, __ATOMIC_RELAXED, __HIP_MEMORY_SCOPE_AGENT);
}

// split fp32 -> (hi, lo) bf16 pair
__device__ __forceinline__ void split8(const float* p, bf16x8& hi, bf16x8& lo) {
    union { __hip_bfloat16 h[8]; bf16x8 v; } uh, ul;
    #pragma unroll
    for (int i = 0; i < 8; ++i) {
        __hip_bfloat16 e = __float2bfloat16(p[i]);
        uh.h[i] = e;
        ul.h[i] = __float2bfloat16(p[i] - __bfloat162float(e));
    }
    hi = uh.v; lo = ul.v;
}

// ---- grid barrier: NO threadfence. __syncthreads drains vmcnt (write-through stores
// are then globally visible); staging reads are sc-flagged so no invalidate needed. ----
__device__ __forceinline__ void gridbar(unsigned* flags, unsigned phase) {
    __syncthreads();                        // drains vmcnt(0): h write-through complete
    if (threadIdx.x == 0)
        __hip_atomic_store(&flags[blockIdx.x * 16], phase,
                           __ATOMIC_RELAXED, __HIP_MEMORY_SCOPE_AGENT);
    if (threadIdx.x < 64) {                 // wave 0: lane i polls block i
        while (__hip_atomic_load(&flags[threadIdx.x * 16],
                                 __ATOMIC_RELAXED, __HIP_MEMORY_SCOPE_AGENT) < phase)
            __builtin_amdgcn_s_sleep(1);
    }
    __syncthreads();
}

// ---------------- dtype probe: 1 = fp32 inputs, 0 = bf16 inputs; zero flags ----------------
__global__ __launch_bounds__(256) void lstm_detect(
    const unsigned* __restrict__ Wq, unsigned* __restrict__ dflag,
    unsigned* __restrict__ flags)
{
    for (int j = threadIdx.x; j < 1024; j += 256) flags[j] = 0;
    if (threadIdx.x == 0) {
        int cnt = 0;
        for (int i = 0; i < 256; ++i) {
            unsigned u = Wq[(size_t)i * 4093];
            float v = b2f((unsigned short)(u & 0xFFFFu));
            if (!(v == v) || fabsf(v) > 100.0f) ++cnt;
        }
        *dflag = (cnt > 32) ? 1u : 0u;
    }
}

// ---------------- init: inputs -> hi/lo state, fp32 c (kernel-end flush publishes) ----------------
__global__ __launch_bounds__(256) void lstm_init(
    const void* __restrict__ h0v, const void* __restrict__ c0v,
    __hip_bfloat16* __restrict__ h0hi, __hip_bfloat16* __restrict__ h0lo,
    __hip_bfloat16* __restrict__ h1hi, __hip_bfloat16* __restrict__ h1lo,
    float* __restrict__ cws, const unsigned* __restrict__ dflag)
{
    const bool f32 = (*dflag != 0);
    int i = blockIdx.x * 256 + threadIdx.x;   // i = b*512 + n
    int b = i >> 9, n = i & 511;
    float f0, f1, g0, g1;
    if (f32) {
        const float* h = (const float*)h0v; const float* c = (const float*)c0v;
        f0 = h[(b * 2 + 0) * 512 + n];  f1 = h[(b * 2 + 1) * 512 + n];
        g0 = c[(b * 2 + 0) * 512 + n];  g1 = c[(b * 2 + 1) * 512 + n];
    } else {
        const unsigned short* h = (const unsigned short*)h0v;
        const unsigned short* c = (const unsigned short*)c0v;
        f0 = b2f(h[(b * 2 + 0) * 512 + n]);  f1 = b2f(h[(b * 2 + 1) * 512 + n]);
        g0 = b2f(c[(b * 2 + 0) * 512 + n]);  g1 = b2f(c[(b * 2 + 1) * 512 + n]);
    }
    __hip_bfloat16 e0 = __float2bfloat16(f0), e1 = __float2bfloat16(f1);
    h0hi[i] = e0; h0lo[i] = __float2bfloat16(f0 - __bfloat162float(e0));
    h1hi[i] = e1; h1lo[i] = __float2bfloat16(f1 - __bfloat162float(e1));
    cws[i] = g0;  cws[16384 + i] = g1;
}

// ---------------- persistent scan: 64 WGs (even=layer0, odd=layer1) ----------------
// Fragment-contiguous LDS: chunk(kk,half,l64) = kk*128 + half*64 + l64, 16B each.
// Tiles: Ah @0, Al @32K, Rh @64K, Rl @96K. gbuf separate, stride 17.
__global__ __launch_bounds__(256, 1) void lstm_seq(
    const void* __restrict__ xv,
    const void* __restrict__ Wxv, const void* __restrict__ bxv,
    const void* __restrict__ Whv, const void* __restrict__ bhv,
    __hip_bfloat16* __restrict__ h0hi, __hip_bfloat16* __restrict__ h0lo,
    __hip_bfloat16* __restrict__ h1hi, __hip_bfloat16* __restrict__ h1lo,
    const float* __restrict__ cws, unsigned* __restrict__ flags,
    const unsigned* __restrict__ dflag, void* __restrict__ outv)
{
    const bool f32 = (*dflag != 0);
    const int p  = blockIdx.x & 1;
    const int wt = blockIdx.x >> 1;
    const int tid = threadIdx.x;
    const int q = tid >> 6, lane = tid & 63;
    const int n16 = lane & 15, quad = lane >> 4;
    const int colg = q * 512 + wt * 16 + n16;

    __shared__ __align__(16) char smem[131072];
    __shared__ float gbuf[2176];              // [4 gates][32 rows] stride 17

    float* outf = (float*)outv;
    __hip_bfloat16* outh = (__hip_bfloat16*)outv;

    // --- weights -> hi(/lo) bf16 fragments, register-resident for all 512 steps ---
    bf16x8 wa[16], wal[16], wr[16], wrl[16];
    if (f32) {
        const float* WA = (const float*)Wxv + ((size_t)(p * 2048 + colg)) * 512;
        const float* WR = (const float*)Whv + ((size_t)(p * 2048 + colg)) * 512;
        #pragma unroll
        for (int kk = 0; kk < 16; ++kk) {
            split8(WA + kk * 32 + quad * 8, wa[kk], wal[kk]);
            split8(WR + kk * 32 + quad * 8, wr[kk], wrl[kk]);
        }
    } else {
        const unsigned short* WA = (const unsigned short*)Wxv + ((size_t)(p * 2048 + colg)) * 512;
        const unsigned short* WR = (const unsigned short*)Whv + ((size_t)(p * 2048 + colg)) * 512;
        union { uint4 u; bf16x8 v; } cvu;
        #pragma unroll
        for (int kk = 0; kk < 16; ++kk) {
            cvu.u = *(const uint4*)(WA + kk * 32 + quad * 8); wa[kk] = cvu.v;
            cvu.u = *(const uint4*)(WR + kk * 32 + quad * 8); wr[kk] = cvu.v;
        }
    }
    float bias;
    if (f32) bias = ((const float*)bxv)[p * 2048 + colg] + ((const float*)bhv)[p * 2048 + colg];
    else     bias = b2f(((const unsigned short*)bxv)[p * 2048 + colg])
                  + b2f(((const unsigned short*)bhv)[p * 2048 + colg]);

    // pointwise mapping: elems (b, n0) and (b, n0+1); fp32 c-state in registers
    const int e0 = tid * 2;
    const int pbb = e0 >> 4;
    const int pn0 = e0 & 15;
    float cv[2];
    cv[0] = cws[p * 16384 + pbb * 512 + wt * 16 + pn0];
    cv[1] = cws[p * 16384 + pbb * 512 + wt * 16 + pn0 + 1];

    const unsigned short* xb = (const unsigned short*)xv;

    // x prefetch (p==0, bf16 mode): stage x(t) into Ah tile — plain cached loads
    #define STAGE_X_BF16(T)                                                      \
        { _Pragma("unroll")                                                      \
          for (int j = 0; j < 8; ++j) {                                          \
              int L = j * 256 + tid;                                             \
              int rem = L & 127;                                                 \
              int row = ((rem >> 6) << 4) + (rem & 15);                          \
              int kcol = ((L >> 7) << 5) + (((rem >> 4) & 3) << 3);              \
              *(uint4*)(smem + (L << 4)) =                                       \
                  *(const uint4*)(xb + ((size_t)row * 512 + (T)) * 512 + kcol);  \
          } }

    if (p == 0 && !f32) STAGE_X_BF16(0);

    for (int k = 0; k <= 512; ++k) {
        const bool doComp = (p == 0) ? (k < 512) : (k > 0);

        if (doComp) {
            const int t = (p == 0) ? k : (k - 1);
            const __hip_bfloat16* Ahi = h0hi + (k & 1) * 16384;          // p==1 A
            const __hip_bfloat16* Alo = h0lo + (k & 1) * 16384;
            const __hip_bfloat16* Rhi = (p == 0) ? h0hi + (k & 1) * 16384
                                                 : h1hi + ((k + 1) & 1) * 16384;
            const __hip_bfloat16* Rlo = (p == 0) ? h0lo + (k & 1) * 16384
                                                 : h1lo + ((k + 1) & 1) * 16384;

            // ---- single-stage staging; h state via agent-scope (coherent) 8B loads ----
            #pragma unroll
            for (int j = 0; j < 8; ++j) {
                int L = j * 256 + tid;
                int rem = L & 127;
                int row = ((rem >> 6) << 4) + (rem & 15);
                int kcol = ((L >> 7) << 5) + (((rem >> 4) & 3) << 3);
                size_t hoff = (size_t)row * 512 + kcol;   // bf16 elems; 16B = 2x u64
                u64 r0 = gload8(Rhi + hoff), r1 = gload8(Rhi + hoff + 4);
                u64 l0 = gload8(Rlo + hoff), l1 = gload8(Rlo + hoff + 4);
                ((u64*)(smem + 65536 + (L << 4)))[0] = r0;
                ((u64*)(smem + 65536 + (L << 4)))[1] = r1;
                ((u64*)(smem + 98304 + (L << 4)))[0] = l0;
                ((u64*)(smem + 98304 + (L << 4)))[1] = l1;
                if (p == 1) {
                    u64 a0 = gload8(Ahi + hoff), a1 = gload8(Ahi + hoff + 4);
                    u64 b0 = gload8(Alo + hoff), b1 = gload8(Alo + hoff + 4);
                    ((u64*)(smem + (L << 4)))[0] = a0;
                    ((u64*)(smem + (L << 4)))[1] = a1;
                    ((u64*)(smem + 32768 + (L << 4)))[0] = b0;
                    ((u64*)(smem + 32768 + (L << 4)))[1] = b1;
                } else if (f32) {
                    const float* xp = (const float*)xv + ((size_t)row * 512 + t) * 512 + kcol;
                    bf16x8 hi, lo;
                    split8(xp, hi, lo);
                    *(bf16x8*)(smem + (L << 4)) = hi;
                    *(bf16x8*)(smem + 32768 + (L << 4)) = lo;
                }
            }
            __syncthreads();

            // ---- MFMA chains (fragment reads lane-linear) ----
            const char* sl = smem + (lane << 4);
            f32x4 acc0 = {bias, bias, bias, bias};
            f32x4 acc1 = {bias, bias, bias, bias};
            if (f32) {
                #pragma unroll
                for (int kk = 0; kk < 16; ++kk) {
                    bf16x8 Aha = *(const bf16x8*)(sl + kk * 2048);
                    bf16x8 Ahb = *(const bf16x8*)(sl + kk * 2048 + 1024);
                    bf16x8 Ala = *(const bf16x8*)(sl + 32768 + kk * 2048);
                    bf16x8 Alb = *(const bf16x8*)(sl + 32768 + kk * 2048 + 1024);
                    bf16x8 Rha = *(const bf16x8*)(sl + 65536 + kk * 2048);
                    bf16x8 Rhb = *(const bf16x8*)(sl + 65536 + kk * 2048 + 1024);
                    bf16x8 Rla = *(const bf16x8*)(sl + 98304 + kk * 2048);
                    bf16x8 Rlb = *(const bf16x8*)(sl + 98304 + kk * 2048 + 1024);
                    acc0 = MFMA16(Aha, wa[kk], acc0);
                    acc0 = MFMA16(Aha, wal[kk], acc0);
                    acc0 = MFMA16(Ala, wa[kk], acc0);
                    acc0 = MFMA16(Rha, wr[kk], acc0);
                    acc0 = MFMA16(Rha, wrl[kk], acc0);
                    acc0 = MFMA16(Rla, wr[kk], acc0);
                    acc1 = MFMA16(Ahb, wa[kk], acc1);
                    acc1 = MFMA16(Ahb, wal[kk], acc1);
                    acc1 = MFMA16(Alb, wa[kk], acc1);
                    acc1 = MFMA16(Rhb, wr[kk], acc1);
                    acc1 = MFMA16(Rhb, wrl[kk], acc1);
                    acc1 = MFMA16(Rlb, wr[kk], acc1);
                }
            } else if (p == 1) {
                #pragma unroll
                for (int kk = 0; kk < 16; ++kk) {
                    bf16x8 Aha = *(const bf16x8*)(sl + kk * 2048);
                    bf16x8 Ahb = *(const bf16x8*)(sl + kk * 2048 + 1024);
                    bf16x8 Ala = *(const bf16x8*)(sl + 32768 + kk * 2048);
                    bf16x8 Alb = *(const bf16x8*)(sl + 32768 + kk * 2048 + 1024);
                    bf16x8 Rha = *(const bf16x8*)(sl + 65536 + kk * 2048);
                    bf16x8 Rhb = *(const bf16x8*)(sl + 65536 + kk * 2048 + 1024);
                    bf16x8 Rla = *(const bf16x8*)(sl + 98304 + kk * 2048);
                    bf16x8 Rlb = *(const bf16x8*)(sl + 98304 + kk * 2048 + 1024);
                    acc0 = MFMA16(Aha, wa[kk], acc0);
                    acc0 = MFMA16(Ala, wa[kk], acc0);
                    acc0 = MFMA16(Rha, wr[kk], acc0);
                    acc0 = MFMA16(Rla, wr[kk], acc0);
                    acc1 = MFMA16(Ahb, wa[kk], acc1);
                    acc1 = MFMA16(Alb, wa[kk], acc1);
                    acc1 = MFMA16(Rhb, wr[kk], acc1);
                    acc1 = MFMA16(Rlb, wr[kk], acc1);
                }
            } else {
                #pragma unroll
                for (int kk = 0; kk < 16; ++kk) {
                    bf16x8 Aha = *(const bf16x8*)(sl + kk * 2048);
                    bf16x8 Ahb = *(const bf16x8*)(sl + kk * 2048 + 1024);
                    bf16x8 Rha = *(const bf16x8*)(sl + 65536 + kk * 2048);
                    bf16x8 Rhb = *(const bf16x8*)(sl + 65536 + kk * 2048 + 1024);
                    bf16x8 Rla = *(const bf16x8*)(sl + 98304 + kk * 2048);
                    bf16x8 Rlb = *(const bf16x8*)(sl + 98304 + kk * 2048 + 1024);
                    acc0 = MFMA16(Aha, wa[kk], acc0);
                    acc0 = MFMA16(Rha, wr[kk], acc0);
                    acc0 = MFMA16(Rla, wr[kk], acc0);
                    acc1 = MFMA16(Ahb, wa[kk], acc1);
                    acc1 = MFMA16(Rhb, wr[kk], acc1);
                    acc1 = MFMA16(Rlb, wr[kk], acc1);
                }
            }
            __syncthreads();                  // all fragment reads done (LDS reusable)

            // gates -> gbuf (C/D layout: col=lane&15, row=quad*4+reg), stride 17
            #pragma unroll
            for (int r = 0; r < 4; ++r) {
                gbuf[(q * 32 + quad * 4 + r) * 17 + n16]      = acc0[r];
                gbuf[(q * 32 + 16 + quad * 4 + r) * 17 + n16] = acc1[r];
            }
            __syncthreads();

            // ---- pointwise epilogue ----
            __hip_bfloat16* Ohi = (p == 0) ? h0hi + ((k + 1) & 1) * 16384
                                           : h1hi + (k & 1) * 16384;
            __hip_bfloat16* Olo = (p == 0) ? h0lo + ((k + 1) & 1) * 16384
                                           : h1lo + (k & 1) * 16384;
            float rh[2], rc[2];
            #pragma unroll
            for (int j = 0; j < 2; ++j) {
                int n = pn0 + j;
                float ig = gbuf[(0 * 32 + pbb) * 17 + n];
                float fg = gbuf[(1 * 32 + pbb) * 17 + n];
                float gg = gbuf[(2 * 32 + pbb) * 17 + n];
                float og = gbuf[(3 * 32 + pbb) * 17 + n];
                float cnew = sigf(fg) * cv[j] + sigf(ig) * tanhf(gg);
                cv[j] = cnew;
                rc[j] = cnew;
                rh[j] = sigf(og) * tanhf(cnew);
            }
            unsigned phi = 0, plo = 0, pcn = 0;
            #pragma unroll
            for (int j = 0; j < 2; ++j) {
                unsigned short hu = f2u(rh[j]);
                unsigned short lu = f2u(rh[j] - b2f(hu));
                phi |= ((unsigned)hu) << (16 * j);
                plo |= ((unsigned)lu) << (16 * j);
                pcn |= ((unsigned)f2u(rc[j])) << (16 * j);
            }
            const int idx = pbb * 512 + wt * 16 + pn0;
            gstore4(Ohi + idx, phi);          // agent-scope write-through
            gstore4(Olo + idx, plo);
            if (p == 1) {
                size_t oidx = ((size_t)pbb * 512 + t) * 512 + wt * 16 + pn0;
                if (f32) { outf[oidx] = rh[0]; outf[oidx + 1] = rh[1]; }
                else     { *(unsigned*)(outh + oidx) = phi; }
                if (k == 512) {
                    if (f32) {
                        outf[HN_OFF + 16384 + idx] = rh[0]; outf[HN_OFF + 16385 + idx] = rh[1];
                        outf[CN_OFF + 16384 + idx] = rc[0]; outf[CN_OFF + 16385 + idx] = rc[1];
                    } else {
                        *(unsigned*)(outh + HN_OFF + 16384 + idx) = phi;
                        *(unsigned*)(outh + CN_OFF + 16384 + idx) = pcn;
                    }
                }
            } else if (k == 511) {
                if (f32) {
                    outf[HN_OFF + idx] = rh[0]; outf[HN_OFF + idx + 1] = rh[1];
                    outf[CN_OFF + idx] = rc[0]; outf[CN_OFF + idx + 1] = rc[1];
                } else {
                    *(unsigned*)(outh + HN_OFF + idx) = phi;
                    *(unsigned*)(outh + CN_OFF + idx) = pcn;
                }
            }

            // prefetch next x tile (cached; L2 stays warm now) during barrier wait
            if (p == 0 && !f32 && k + 1 < 512) STAGE_X_BF16(k + 1);
        }

        if (k < 512) gridbar(flags, (unsigned)(k + 1));
    }
}

extern "C" void kernel_launch(void* const* d_in, const int* in_sizes, int n_in,
                              void* d_out, int out_size, void* d_ws, size_t ws_size,
                              hipStream_t stream)
{
    const void* x  = d_in[0];
    const void* h0 = d_in[1];
    const void* c0 = d_in[2];
    const void* Wx = d_in[3];
    const void* bx = d_in[4];
    const void* Wh = d_in[5];
    const void* bh = d_in[6];

    char* ws = (char*)d_ws;                                    // total need: ~398 KB
    __hip_bfloat16* h0hi = (__hip_bfloat16*)(ws);              // [2][16384] bf16
    __hip_bfloat16* h0lo = (__hip_bfloat16*)(ws + 65536);
    __hip_bfloat16* h1hi = (__hip_bfloat16*)(ws + 131072);
    __hip_bfloat16* h1lo = (__hip_bfloat16*)(ws + 196608);
    float*          cws  = (float*)(ws + 262144);              // [2][16384] f32
    unsigned*       flags = (unsigned*)(ws + 393216);          // 64 slots x 16 words
    unsigned*       dflag = (unsigned*)(ws + 397312);

    lstm_detect<<<1, 256, 0, stream>>>((const unsigned*)Wx, dflag, flags);
    lstm_init<<<64, 256, 0, stream>>>(h0, c0, h0hi, h0lo, h1hi, h1lo, cws, dflag);
    lstm_seq<<<64, 256, 0, stream>>>(x, Wx, bx, Wh, bh,
                                     h0hi, h0lo, h1hi, h1lo, cws, flags, dflag, d_out);
}

// Round 9
// 6998.083 us; speedup vs baseline: 1.4012x; 1.0202x over previous
//
#include <hip/hip_runtime.h>
#include <hip/hip_bf16.h>

typedef __bf16 bf16x8 __attribute__((ext_vector_type(8)));
typedef float f32x4 __attribute__((ext_vector_type(4)));
typedef unsigned long long u64;

#define MFMA16(a, b, c) __builtin_amdgcn_mfma_f32_16x16x32_bf16((a), (b), (c), 0, 0, 0)

#define HN_OFF 8388608ull   // 32*512*512
#define CN_OFF 8421376ull   // HN_OFF + 2*32*512

__device__ __forceinline__ float sigf(float x) { return 1.0f / (1.0f + __expf(-x)); }
__device__ __forceinline__ float b2f(unsigned short u) {
    union { unsigned u; float f; } c; c.u = ((unsigned)u) << 16; return c.f;
}
__device__ __forceinline__ unsigned short f2u(float f) {
    __hip_bfloat16 h = __float2bfloat16(f); return *(unsigned short*)&h;
}

// agent-scope (cross-XCD coherent) accessors
__device__ __forceinline__ u64 gload8(const void* p) {
    return __hip_atomic_load((const u64*)p, __ATOMIC_RELAXED, __HIP_MEMORY_SCOPE_AGENT);
}
__device__ __forceinline__ void gstore4(void* p, unsigned v) {
    __hip_atomic_store((unsigned*)p, v, __ATOMIC_RELAXED, __HIP_MEMORY_SCOPE_AGENT);
}

// split fp32 -> (hi, lo) bf16 pair
__device__ __forceinline__ void split8(const float* p, bf16x8& hi, bf16x8& lo) {
    union { __hip_bfloat16 h[8]; bf16x8 v; } uh, ul;
    #pragma unroll
    for (int i = 0; i < 8; ++i) {
        __hip_bfloat16 e = __float2bfloat16(p[i]);
        uh.h[i] = e;
        ul.h[i] = __float2bfloat16(p[i] - __bfloat162float(e));
    }
    hi = uh.v; lo = ul.v;
}

// ---------------- dtype probe (wave-parallel): 1 = fp32 inputs, 0 = bf16 ----------------
__global__ __launch_bounds__(256) void lstm_detect(
    const unsigned* __restrict__ Wq, unsigned* __restrict__ dflag,
    unsigned* __restrict__ flags)
{
    for (int j = threadIdx.x; j < 1024; j += 256) flags[j] = 0;
    if (threadIdx.x < 64) {
        int lane = threadIdx.x;
        int bad = 0;
        #pragma unroll
        for (int i = 0; i < 4; ++i) {
            unsigned u = Wq[(size_t)(lane + i * 64) * 4093];
            float v = b2f((unsigned short)(u & 0xFFFFu));
            if (!(v == v) || fabsf(v) > 100.0f) ++bad;
        }
        #pragma unroll
        for (int off = 32; off; off >>= 1) bad += __shfl_down(bad, off, 64);
        if (lane == 0) *dflag = (bad > 32) ? 1u : 0u;
    }
}

// ---------------- init: inputs -> hi/lo state, fp32 c ----------------
__global__ __launch_bounds__(256) void lstm_init(
    const void* __restrict__ h0v, const void* __restrict__ c0v,
    __hip_bfloat16* __restrict__ h0hi, __hip_bfloat16* __restrict__ h0lo,
    __hip_bfloat16* __restrict__ h1hi, __hip_bfloat16* __restrict__ h1lo,
    float* __restrict__ cws, const unsigned* __restrict__ dflag)
{
    const bool f32 = (*dflag != 0);
    int i = blockIdx.x * 256 + threadIdx.x;   // i = b*512 + n
    int b = i >> 9, n = i & 511;
    float f0, f1, g0, g1;
    if (f32) {
        const float* h = (const float*)h0v; const float* c = (const float*)c0v;
        f0 = h[(b * 2 + 0) * 512 + n];  f1 = h[(b * 2 + 1) * 512 + n];
        g0 = c[(b * 2 + 0) * 512 + n];  g1 = c[(b * 2 + 1) * 512 + n];
    } else {
        const unsigned short* h = (const unsigned short*)h0v;
        const unsigned short* c = (const unsigned short*)c0v;
        f0 = b2f(h[(b * 2 + 0) * 512 + n]);  f1 = b2f(h[(b * 2 + 1) * 512 + n]);
        g0 = b2f(c[(b * 2 + 0) * 512 + n]);  g1 = b2f(c[(b * 2 + 1) * 512 + n]);
    }
    __hip_bfloat16 e0 = __float2bfloat16(f0), e1 = __float2bfloat16(f1);
    h0hi[i] = e0; h0lo[i] = __float2bfloat16(f0 - __bfloat162float(e0));
    h1hi[i] = e1; h1lo[i] = __float2bfloat16(f1 - __bfloat162float(e1));
    cws[i] = g0;  cws[16384 + i] = g1;
}

// ---------------- persistent scan: 64 WGs (even=layer0, odd=layer1) ----------------
// Fragment-contiguous LDS tiles: Ah @0, Al @32K, Rh @64K, Rl @96K; gbuf stride 17.
__global__ __launch_bounds__(256, 1) void lstm_seq(
    const void* __restrict__ xv,
    const void* __restrict__ Wxv, const void* __restrict__ bxv,
    const void* __restrict__ Whv, const void* __restrict__ bhv,
    __hip_bfloat16* __restrict__ h0hi, __hip_bfloat16* __restrict__ h0lo,
    __hip_bfloat16* __restrict__ h1hi, __hip_bfloat16* __restrict__ h1lo,
    const float* __restrict__ cws, unsigned* __restrict__ flags,
    const unsigned* __restrict__ dflag, void* __restrict__ outv)
{
    const bool f32 = (*dflag != 0);
    const int p  = blockIdx.x & 1;
    const int wt = blockIdx.x >> 1;
    const int tid = threadIdx.x;
    const int q = tid >> 6, lane = tid & 63;
    const int n16 = lane & 15, quad = lane >> 4;
    const int colg = q * 512 + wt * 16 + n16;

    __shared__ __align__(16) char smem[131072];
    __shared__ float gbuf[2176];              // [4 gates][32 rows] stride 17

    float* outf = (float*)outv;
    __hip_bfloat16* outh = (__hip_bfloat16*)outv;

    // --- weights -> hi(/lo) bf16 fragments, register-resident for all 512 steps ---
    bf16x8 wa[16], wal[16], wr[16], wrl[16];
    if (f32) {
        const float* WA = (const float*)Wxv + ((size_t)(p * 2048 + colg)) * 512;
        const float* WR = (const float*)Whv + ((size_t)(p * 2048 + colg)) * 512;
        #pragma unroll
        for (int kk = 0; kk < 16; ++kk) {
            split8(WA + kk * 32 + quad * 8, wa[kk], wal[kk]);
            split8(WR + kk * 32 + quad * 8, wr[kk], wrl[kk]);
        }
    } else {
        const unsigned short* WA = (const unsigned short*)Wxv + ((size_t)(p * 2048 + colg)) * 512;
        const unsigned short* WR = (const unsigned short*)Whv + ((size_t)(p * 2048 + colg)) * 512;
        union { uint4 u; bf16x8 v; } cvu;
        #pragma unroll
        for (int kk = 0; kk < 16; ++kk) {
            cvu.u = *(const uint4*)(WA + kk * 32 + quad * 8); wa[kk] = cvu.v;
            cvu.u = *(const uint4*)(WR + kk * 32 + quad * 8); wr[kk] = cvu.v;
        }
    }
    float bias;
    if (f32) bias = ((const float*)bxv)[p * 2048 + colg] + ((const float*)bhv)[p * 2048 + colg];
    else     bias = b2f(((const unsigned short*)bxv)[p * 2048 + colg])
                  + b2f(((const unsigned short*)bhv)[p * 2048 + colg]);

    // pointwise mapping: elems (b, n0), (b, n0+1); fp32 c-state in registers
    const int e0 = tid * 2;
    const int pbb = e0 >> 4;
    const int pn0 = e0 & 15;
    float cv[2];
    cv[0] = cws[p * 16384 + pbb * 512 + wt * 16 + pn0];
    cv[1] = cws[p * 16384 + pbb * 512 + wt * 16 + pn0 + 1];

    const unsigned short* xb = (const unsigned short*)xv;

    #define STAGE_X_BF16(T)                                                      \
        { _Pragma("unroll")                                                      \
          for (int j = 0; j < 8; ++j) {                                          \
              int L = j * 256 + tid;                                             \
              int rem = L & 127;                                                 \
              int row = ((rem >> 6) << 4) + (rem & 15);                          \
              int kcol = ((L >> 7) << 5) + (((rem >> 4) & 3) << 3);              \
              *(uint4*)(smem + (L << 4)) =                                       \
                  *(const uint4*)(xb + ((size_t)row * 512 + (T)) * 512 + kcol);  \
          } }

    if (p == 0 && !f32) STAGE_X_BF16(0);

    for (int k = 0; k <= 512; ++k) {
        const bool doComp = (p == 0) ? (k < 512) : (k > 0);

        if (doComp) {
            const int t = (p == 0) ? k : (k - 1);
            const __hip_bfloat16* Ahi = h0hi + (k & 1) * 16384;
            const __hip_bfloat16* Alo = h0lo + (k & 1) * 16384;
            const __hip_bfloat16* Rhi = (p == 0) ? h0hi + (k & 1) * 16384
                                                 : h1hi + ((k + 1) & 1) * 16384;
            const __hip_bfloat16* Rlo = (p == 0) ? h0lo + (k & 1) * 16384
                                                 : h1lo + ((k + 1) & 1) * 16384;

            // ---- staging: gather-then-scatter (all agent loads in flight, one drain) ----
            if (p == 1) {
                #pragma unroll
                for (int hp = 0; hp < 2; ++hp) {
                    u64 vA[8], vB[8], vR[8], vL[8];
                    #pragma unroll
                    for (int jj = 0; jj < 4; ++jj) {
                        int L = (hp * 4 + jj) * 256 + tid;
                        int rem = L & 127;
                        int row = ((rem >> 6) << 4) + (rem & 15);
                        int kcol = ((L >> 7) << 5) + (((rem >> 4) & 3) << 3);
                        size_t hoff = (size_t)row * 512 + kcol;
                        vA[jj*2] = gload8(Ahi + hoff); vA[jj*2+1] = gload8(Ahi + hoff + 4);
                        vB[jj*2] = gload8(Alo + hoff); vB[jj*2+1] = gload8(Alo + hoff + 4);
                        vR[jj*2] = gload8(Rhi + hoff); vR[jj*2+1] = gload8(Rhi + hoff + 4);
                        vL[jj*2] = gload8(Rlo + hoff); vL[jj*2+1] = gload8(Rlo + hoff + 4);
                    }
                    #pragma unroll
                    for (int jj = 0; jj < 4; ++jj) {
                        int L = (hp * 4 + jj) * 256 + tid;
                        u64* dA = (u64*)(smem + (L << 4));
                        u64* dB = (u64*)(smem + 32768 + (L << 4));
                        u64* dR = (u64*)(smem + 65536 + (L << 4));
                        u64* dL = (u64*)(smem + 98304 + (L << 4));
                        dA[0] = vA[jj*2]; dA[1] = vA[jj*2+1];
                        dB[0] = vB[jj*2]; dB[1] = vB[jj*2+1];
                        dR[0] = vR[jj*2]; dR[1] = vR[jj*2+1];
                        dL[0] = vL[jj*2]; dL[1] = vL[jj*2+1];
                    }
                }
            } else {
                u64 vR[16], vL[16];
                #pragma unroll
                for (int j = 0; j < 8; ++j) {
                    int L = j * 256 + tid;
                    int rem = L & 127;
                    int row = ((rem >> 6) << 4) + (rem & 15);
                    int kcol = ((L >> 7) << 5) + (((rem >> 4) & 3) << 3);
                    size_t hoff = (size_t)row * 512 + kcol;
                    vR[j*2] = gload8(Rhi + hoff); vR[j*2+1] = gload8(Rhi + hoff + 4);
                    vL[j*2] = gload8(Rlo + hoff); vL[j*2+1] = gload8(Rlo + hoff + 4);
                }
                #pragma unroll
                for (int j = 0; j < 8; ++j) {
                    int L = j * 256 + tid;
                    u64* dR = (u64*)(smem + 65536 + (L << 4));
                    u64* dL = (u64*)(smem + 98304 + (L << 4));
                    dR[0] = vR[j*2]; dR[1] = vR[j*2+1];
                    dL[0] = vL[j*2]; dL[1] = vL[j*2+1];
                }
                if (f32) {
                    #pragma unroll
                    for (int j = 0; j < 8; ++j) {
                        int L = j * 256 + tid;
                        int rem = L & 127;
                        int row = ((rem >> 6) << 4) + (rem & 15);
                        int kcol = ((L >> 7) << 5) + (((rem >> 4) & 3) << 3);
                        const float* xp = (const float*)xv + ((size_t)row * 512 + t) * 512 + kcol;
                        bf16x8 hi, lo;
                        split8(xp, hi, lo);
                        *(bf16x8*)(smem + (L << 4)) = hi;
                        *(bf16x8*)(smem + 32768 + (L << 4)) = lo;
                    }
                }
            }
            __syncthreads();

            // ---- MFMA chains ----
            const char* sl = smem + (lane << 4);
            f32x4 acc0 = {bias, bias, bias, bias};
            f32x4 acc1 = {bias, bias, bias, bias};
            if (f32) {
                #pragma unroll
                for (int kk = 0; kk < 16; ++kk) {
                    bf16x8 Aha = *(const bf16x8*)(sl + kk * 2048);
                    bf16x8 Ahb = *(const bf16x8*)(sl + kk * 2048 + 1024);
                    bf16x8 Ala = *(const bf16x8*)(sl + 32768 + kk * 2048);
                    bf16x8 Alb = *(const bf16x8*)(sl + 32768 + kk * 2048 + 1024);
                    bf16x8 Rha = *(const bf16x8*)(sl + 65536 + kk * 2048);
                    bf16x8 Rhb = *(const bf16x8*)(sl + 65536 + kk * 2048 + 1024);
                    bf16x8 Rla = *(const bf16x8*)(sl + 98304 + kk * 2048);
                    bf16x8 Rlb = *(const bf16x8*)(sl + 98304 + kk * 2048 + 1024);
                    acc0 = MFMA16(Aha, wa[kk], acc0);
                    acc0 = MFMA16(Aha, wal[kk], acc0);
                    acc0 = MFMA16(Ala, wa[kk], acc0);
                    acc0 = MFMA16(Rha, wr[kk], acc0);
                    acc0 = MFMA16(Rha, wrl[kk], acc0);
                    acc0 = MFMA16(Rla, wr[kk], acc0);
                    acc1 = MFMA16(Ahb, wa[kk], acc1);
                    acc1 = MFMA16(Ahb, wal[kk], acc1);
                    acc1 = MFMA16(Alb, wa[kk], acc1);
                    acc1 = MFMA16(Rhb, wr[kk], acc1);
                    acc1 = MFMA16(Rhb, wrl[kk], acc1);
                    acc1 = MFMA16(Rlb, wr[kk], acc1);
                }
            } else if (p == 1) {
                #pragma unroll
                for (int kk = 0; kk < 16; ++kk) {
                    bf16x8 Aha = *(const bf16x8*)(sl + kk * 2048);
                    bf16x8 Ahb = *(const bf16x8*)(sl + kk * 2048 + 1024);
                    bf16x8 Ala = *(const bf16x8*)(sl + 32768 + kk * 2048);
                    bf16x8 Alb = *(const bf16x8*)(sl + 32768 + kk * 2048 + 1024);
                    bf16x8 Rha = *(const bf16x8*)(sl + 65536 + kk * 2048);
                    bf16x8 Rhb = *(const bf16x8*)(sl + 65536 + kk * 2048 + 1024);
                    bf16x8 Rla = *(const bf16x8*)(sl + 98304 + kk * 2048);
                    bf16x8 Rlb = *(const bf16x8*)(sl + 98304 + kk * 2048 + 1024);
                    acc0 = MFMA16(Aha, wa[kk], acc0);
                    acc0 = MFMA16(Ala, wa[kk], acc0);
                    acc0 = MFMA16(Rha, wr[kk], acc0);
                    acc0 = MFMA16(Rla, wr[kk], acc0);
                    acc1 = MFMA16(Ahb, wa[kk], acc1);
                    acc1 = MFMA16(Alb, wa[kk], acc1);
                    acc1 = MFMA16(Rhb, wr[kk], acc1);
                    acc1 = MFMA16(Rlb, wr[kk], acc1);
                }
            } else {
                #pragma unroll
                for (int kk = 0; kk < 16; ++kk) {
                    bf16x8 Aha = *(const bf16x8*)(sl + kk * 2048);
                    bf16x8 Ahb = *(const bf16x8*)(sl + kk * 2048 + 1024);
                    bf16x8 Rha = *(const bf16x8*)(sl + 65536 + kk * 2048);
                    bf16x8 Rhb = *(const bf16x8*)(sl + 65536 + kk * 2048 + 1024);
                    bf16x8 Rla = *(const bf16x8*)(sl + 98304 + kk * 2048);
                    bf16x8 Rlb = *(const bf16x8*)(sl + 98304 + kk * 2048 + 1024);
                    acc0 = MFMA16(Aha, wa[kk], acc0);
                    acc0 = MFMA16(Rha, wr[kk], acc0);
                    acc0 = MFMA16(Rla, wr[kk], acc0);
                    acc1 = MFMA16(Ahb, wa[kk], acc1);
                    acc1 = MFMA16(Rhb, wr[kk], acc1);
                    acc1 = MFMA16(Rlb, wr[kk], acc1);
                }
            }
            __syncthreads();

            #pragma unroll
            for (int r = 0; r < 4; ++r) {
                gbuf[(q * 32 + quad * 4 + r) * 17 + n16]      = acc0[r];
                gbuf[(q * 32 + 16 + quad * 4 + r) * 17 + n16] = acc1[r];
            }
            __syncthreads();

            // ---- pointwise epilogue ----
            __hip_bfloat16* Ohi = (p == 0) ? h0hi + ((k + 1) & 1) * 16384
                                           : h1hi + (k & 1) * 16384;
            __hip_bfloat16* Olo = (p == 0) ? h0lo + ((k + 1) & 1) * 16384
                                           : h1lo + (k & 1) * 16384;
            float rh[2], rc[2];
            #pragma unroll
            for (int j = 0; j < 2; ++j) {
                int n = pn0 + j;
                float ig = gbuf[(0 * 32 + pbb) * 17 + n];
                float fg = gbuf[(1 * 32 + pbb) * 17 + n];
                float gg = gbuf[(2 * 32 + pbb) * 17 + n];
                float og = gbuf[(3 * 32 + pbb) * 17 + n];
                float cnew = sigf(fg) * cv[j] + sigf(ig) * tanhf(gg);
                cv[j] = cnew;
                rc[j] = cnew;
                rh[j] = sigf(og) * tanhf(cnew);
            }
            unsigned phi = 0, plo = 0, pcn = 0;
            #pragma unroll
            for (int j = 0; j < 2; ++j) {
                unsigned short hu = f2u(rh[j]);
                unsigned short lu = f2u(rh[j] - b2f(hu));
                phi |= ((unsigned)hu) << (16 * j);
                plo |= ((unsigned)lu) << (16 * j);
                pcn |= ((unsigned)f2u(rc[j])) << (16 * j);
            }
            const int idx = pbb * 512 + wt * 16 + pn0;
            gstore4(Ohi + idx, phi);
            gstore4(Olo + idx, plo);

            // ---- publish ASAP: drain h stores, then flag; defer out/prefetch ----
            __syncthreads();
            if (k < 512 && tid == 0)
                __hip_atomic_store(&flags[blockIdx.x * 16], (unsigned)(k + 1),
                                   __ATOMIC_RELAXED, __HIP_MEMORY_SCOPE_AGENT);

            if (p == 1) {
                size_t oidx = ((size_t)pbb * 512 + t) * 512 + wt * 16 + pn0;
                if (f32) { outf[oidx] = rh[0]; outf[oidx + 1] = rh[1]; }
                else     { *(unsigned*)(outh + oidx) = phi; }
                if (k == 512) {
                    if (f32) {
                        outf[HN_OFF + 16384 + idx] = rh[0]; outf[HN_OFF + 16385 + idx] = rh[1];
                        outf[CN_OFF + 16384 + idx] = rc[0]; outf[CN_OFF + 16385 + idx] = rc[1];
                    } else {
                        *(unsigned*)(outh + HN_OFF + 16384 + idx) = phi;
                        *(unsigned*)(outh + CN_OFF + 16384 + idx) = pcn;
                    }
                }
            } else if (k == 511) {
                if (f32) {
                    outf[HN_OFF + idx] = rh[0]; outf[HN_OFF + idx + 1] = rh[1];
                    outf[CN_OFF + idx] = rc[0]; outf[CN_OFF + idx + 1] = rc[1];
                } else {
                    *(unsigned*)(outh + HN_OFF + idx) = phi;
                    *(unsigned*)(outh + CN_OFF + idx) = pcn;
                }
            }
            if (p == 0 && !f32 && k + 1 < 512) STAGE_X_BF16(k + 1);
        } else {
            // p==1 at k==0 (or p==0 at k==512): nothing computed this phase
            if (k < 512 && tid == 0)
                __hip_atomic_store(&flags[blockIdx.x * 16], (unsigned)(k + 1),
                                   __ATOMIC_RELAXED, __HIP_MEMORY_SCOPE_AGENT);
        }

        if (k < 512) {
            if (tid < 64) {
                while (__hip_atomic_load(&flags[tid * 16],
                                         __ATOMIC_RELAXED, __HIP_MEMORY_SCOPE_AGENT)
                       < (unsigned)(k + 1))
                    __builtin_amdgcn_s_sleep(1);
            }
            __syncthreads();
        }
    }
}

extern "C" void kernel_launch(void* const* d_in, const int* in_sizes, int n_in,
                              void* d_out, int out_size, void* d_ws, size_t ws_size,
                              hipStream_t stream)
{
    const void* x  = d_in[0];
    const void* h0 = d_in[1];
    const void* c0 = d_in[2];
    const void* Wx = d_in[3];
    const void* bx = d_in[4];
    const void* Wh = d_in[5];
    const void* bh = d_in[6];

    char* ws = (char*)d_ws;                                    // total need: ~398 KB
    __hip_bfloat16* h0hi = (__hip_bfloat16*)(ws);              // [2][16384] bf16
    __hip_bfloat16* h0lo = (__hip_bfloat16*)(ws + 65536);
    __hip_bfloat16* h1hi = (__hip_bfloat16*)(ws + 131072);
    __hip_bfloat16* h1lo = (__hip_bfloat16*)(ws + 196608);
    float*          cws  = (float*)(ws + 262144);              // [2][16384] f32
    unsigned*       flags = (unsigned*)(ws + 393216);          // 64 slots x 16 words
    unsigned*       dflag = (unsigned*)(ws + 397312);

    lstm_detect<<<1, 256, 0, stream>>>((const unsigned*)Wx, dflag, flags);
    lstm_init<<<64, 256, 0, stream>>>(h0, c0, h0hi, h0lo, h1hi, h1lo, cws, dflag);
    lstm_seq<<<64, 256, 0, stream>>>(x, Wx, bx, Wh, bh,
                                     h0hi, h0lo, h1hi, h1lo, cws, flags, dflag, d_out);
}